// Round 1
// baseline (806.143 us; speedup 1.0000x reference)
//
#include <hip/hip_runtime.h>
#include <math.h>

// Problem constants
#define Bn   4
#define Cc   64
#define Hh   128
#define Ww   128
#define Oo   64
#define HW   (Hh * Ww)          // 16384
#define CIN  128                // 2*C
#define KK   9
#define NPAR 27                 // py[9] px[9] m[9]

// Workspace layout (float offsets)
#define WOM_OFF 0                        // [CIN][27][9]  = 31104 floats
#define WT_OFF  (CIN * 27 * 9)           // [C][KK][Oo]   = 36864 floats
#define PAR_OFF (WT_OFF + Cc * KK * Oo)  // [B][27][HW]   = 1769472 floats

// ---------------------------------------------------------------------------
// Prepass: reorder weights for wave-uniform (scalar-load) access in hot loops.
//   wom[c][j][k] = j<18 ? w_off[j][c][k] : w_mod[j-18][c][k]
//   wT [c][k][o] = w_reg[o][c][k]
// ---------------------------------------------------------------------------
__global__ void prep_weights(const float* __restrict__ w_off,
                             const float* __restrict__ w_mod,
                             const float* __restrict__ w_reg,
                             float* __restrict__ ws) {
    int i = blockIdx.x * blockDim.x + threadIdx.x;
    const int n_wom = CIN * 27 * 9;       // 31104
    const int n_wt  = Cc * KK * Oo;       // 36864
    if (i < n_wom) {
        int k = i % 9;
        int j = (i / 9) % 27;
        int c = i / (9 * 27);
        float v = (j < 18) ? w_off[(j * CIN + c) * 9 + k]
                           : w_mod[((j - 18) * CIN + c) * 9 + k];
        ws[WOM_OFF + i] = v;
    }
    if (i < n_wt) {
        int o = i % Oo;
        int k = (i / Oo) % KK;
        int c = i / (Oo * KK);
        ws[WT_OFF + i] = w_reg[(o * Cc + c) * 9 + k];
    }
}

// ---------------------------------------------------------------------------
// Conv1: 3x3 conv, 128 -> 27 channels over fea = concat(x, guide).
// 16x16 pixel tile per block (256 threads). LDS-stage 18x18 input planes,
// 4 channels per barrier. Weights via wave-uniform scalar loads.
// Epilogue writes sampling params planar: [b][ch][HW], ch 0..8=py 9..17=px
// 18..26=mask.
// ---------------------------------------------------------------------------
#define TS   16
#define TP   18
#define LSTR 20
#define CPS  4

__global__ __launch_bounds__(256)
void conv_offmod(const float* __restrict__ x, const float* __restrict__ g,
                 const float* __restrict__ b_off, const float* __restrict__ b_mod,
                 float* __restrict__ ws) {
    __shared__ float tile[CPS][TP * LSTR];

    const int tid = threadIdx.x;
    const int tx = tid & 15, ty = tid >> 4;
    const int bx = blockIdx.x, by = blockIdx.y, b = blockIdx.z;
    const int ho = by * TS + ty, wo = bx * TS + tx;
    const int gy0 = by * TS - 1, gx0 = bx * TS - 1;

    const float* wom = ws + WOM_OFF;

    float acc[27];
#pragma unroll
    for (int j = 0; j < 27; j++) acc[j] = 0.f;

    for (int c0 = 0; c0 < CIN; c0 += CPS) {
        __syncthreads();
        for (int idx = tid; idx < CPS * TP * TP; idx += 256) {
            int plane = idx / (TP * TP);
            int rem = idx - plane * (TP * TP);
            int r = rem / TP, col = rem - r * TP;
            int c = c0 + plane;
            const float* src = (c < Cc) ? (x + ((size_t)(b * Cc + c) << 14))
                                        : (g + ((size_t)(b * Cc + (c - Cc)) << 14));
            int gy = gy0 + r, gx = gx0 + col;
            float v = 0.f;
            if ((unsigned)gy < (unsigned)Hh && (unsigned)gx < (unsigned)Ww)
                v = src[(gy << 7) + gx];
            tile[plane][r * LSTR + col] = v;
        }
        __syncthreads();

        for (int p = 0; p < CPS; p++) {
            int c = c0 + p;
            float v[9];
#pragma unroll
            for (int dy = 0; dy < 3; dy++)
#pragma unroll
                for (int dx = 0; dx < 3; dx++)
                    v[dy * 3 + dx] = tile[p][(ty + dy) * LSTR + (tx + dx)];
            const float* wr = wom + c * 243;   // uniform address -> s_load
#pragma unroll
            for (int j = 0; j < 27; j++) {
                float s = 0.f;
#pragma unroll
                for (int k = 0; k < 9; k++) s += wr[j * 9 + k] * v[k];
                acc[j] += s;
            }
        }
    }

    // Epilogue: sampling coordinates + modulator
    const int pix = (ho << 7) + wo;
    float* par = ws + PAR_OFF + (size_t)b * NPAR * HW;
#pragma unroll
    for (int k = 0; k < 9; k++) {
        float oy = acc[2 * k] + b_off[2 * k];
        float ox = acc[2 * k + 1] + b_off[2 * k + 1];
        float py = oy + (float)(k / 3) + (float)(ho - 1);
        float px = ox + (float)(k % 3) + (float)(wo - 1);
        float mv = acc[18 + k] + b_mod[k];
        float m = 2.f / (1.f + __expf(-mv));
        par[k * HW + pix]        = py;
        par[(9 + k) * HW + pix]  = px;
        par[(18 + k) * HW + pix] = m;
    }
}

// ---------------------------------------------------------------------------
// Deformable conv: per pixel, 9 taps bilinear-gather over 64 channels, then
// 64x576 dot with w_reg. One wave per block, 8x8 pixel tile, output channels
// split in halves of 32 (z = b*2 + half) for occupancy.
// ---------------------------------------------------------------------------
__global__ __launch_bounds__(64)
void deform_gemm(const float* __restrict__ x, const float* __restrict__ ws_,
                 float* __restrict__ out) {
    const int t = threadIdx.x;
    const int bx = blockIdx.x, by = blockIdx.y;
    const int b = blockIdx.z >> 1, half = blockIdx.z & 1;
    const int ho = by * 8 + (t >> 3), wo = bx * 8 + (t & 7);
    const int pix = (ho << 7) + wo;

    const float* par = ws_ + PAR_OFF + (size_t)b * NPAR * HW + pix;
    const float* wT  = ws_ + WT_OFF + half * 32;

    float w00[9], w01[9], w10[9], w11[9];
    int   i00[9], i01[9], i10[9], i11[9];
#pragma unroll
    for (int k = 0; k < 9; k++) {
        float py = par[k * HW];
        float px = par[(9 + k) * HW];
        float m  = par[(18 + k) * HW];
        float fy = floorf(py), fx = floorf(px);
        int y0 = (int)fy, x0 = (int)fx;
        int y1 = y0 + 1, x1 = x0 + 1;
        float wy1 = py - fy, wx1 = px - fx;
        float wy0 = 1.f - wy1, wx0 = 1.f - wx1;
        bool vy0 = (unsigned)y0 < (unsigned)Hh, vy1 = (unsigned)y1 < (unsigned)Hh;
        bool vx0 = (unsigned)x0 < (unsigned)Ww, vx1 = (unsigned)x1 < (unsigned)Ww;
        int cy0 = min(max(y0, 0), Hh - 1), cy1 = min(max(y1, 0), Hh - 1);
        int cx0 = min(max(x0, 0), Ww - 1), cx1 = min(max(x1, 0), Ww - 1);
        w00[k] = (vy0 && vx0) ? wy0 * wx0 * m : 0.f;
        w01[k] = (vy0 && vx1) ? wy0 * wx1 * m : 0.f;
        w10[k] = (vy1 && vx0) ? wy1 * wx0 * m : 0.f;
        w11[k] = (vy1 && vx1) ? wy1 * wx1 * m : 0.f;
        i00[k] = (cy0 << 7) + cx0; i01[k] = (cy0 << 7) + cx1;
        i10[k] = (cy1 << 7) + cx0; i11[k] = (cy1 << 7) + cx1;
    }

    float acc[32];
#pragma unroll
    for (int o = 0; o < 32; o++) acc[o] = 0.f;

    const float* xb = x + ((size_t)(b * Cc) << 14);
    for (int c = 0; c < Cc; c++) {
        const float* xp = xb + ((size_t)c << 14);
#pragma unroll
        for (int k = 0; k < 9; k++) {
            float val = w00[k] * xp[i00[k]] + w01[k] * xp[i01[k]]
                      + w10[k] * xp[i10[k]] + w11[k] * xp[i11[k]];
            const float* wr = wT + (c * 9 + k) * 64;   // uniform -> s_load
#pragma unroll
            for (int o = 0; o < 32; o++) acc[o] += wr[o] * val;
        }
    }

    float* op = out + ((size_t)(b * Oo + half * 32) << 14) + pix;
#pragma unroll
    for (int o = 0; o < 32; o++) op[(size_t)o << 14] = acc[o];
}

// ---------------------------------------------------------------------------
extern "C" void kernel_launch(void* const* d_in, const int* in_sizes, int n_in,
                              void* d_out, int out_size, void* d_ws, size_t ws_size,
                              hipStream_t stream) {
    const float* x     = (const float*)d_in[0];
    const float* guide = (const float*)d_in[1];
    const float* w_off = (const float*)d_in[2];
    const float* b_off = (const float*)d_in[3];
    const float* w_mod = (const float*)d_in[4];
    const float* b_mod = (const float*)d_in[5];
    const float* w_reg = (const float*)d_in[6];
    float* out = (float*)d_out;
    float* ws  = (float*)d_ws;

    hipLaunchKernelGGL(prep_weights, dim3((Cc * KK * Oo + 255) / 256), dim3(256),
                       0, stream, w_off, w_mod, w_reg, ws);
    hipLaunchKernelGGL(conv_offmod, dim3(Ww / TS, Hh / TS, Bn), dim3(256),
                       0, stream, x, guide, b_off, b_mod, ws);
    hipLaunchKernelGGL(deform_gemm, dim3(Ww / 8, Hh / 8, Bn * 2), dim3(64),
                       0, stream, x, ws, out);
}

// Round 2
// 799.548 us; speedup vs baseline: 1.0082x; 1.0082x over previous
//
#include <hip/hip_runtime.h>
#include <math.h>

// Problem constants
#define Bn   4
#define Cc   64
#define Hh   128
#define Ww   128
#define Oo   64
#define HW   (Hh * Ww)          // 16384
#define CIN  128                // 2*C
#define KK   9
#define NPAR 27                 // py[9] px[9] m[9]
#define NSPL 4                  // conv channel-split groups

// Workspace layout (float offsets)
#define WOM_OFF  0                         // [CIN][27][9]  = 31104 floats
#define WT_OFF   (CIN * 27 * 9)            // [C][KK][Oo]   = 36864 floats
#define PAR1_OFF (WT_OFF + Cc * KK * Oo)   // fallback par [B][27][HW]
#define PART_OFF PAR1_OFF                  // big path: partials [4][B][27][HW]
#define PAR2_OFF (PART_OFF + NSPL * Bn * NPAR * HW)
#define WS_NEED_FLOATS (PAR2_OFF + Bn * NPAR * HW)

// ---------------------------------------------------------------------------
// Prepass: reorder weights for wave-uniform (scalar-load) access in hot loops.
// ---------------------------------------------------------------------------
__global__ void prep_weights(const float* __restrict__ w_off,
                             const float* __restrict__ w_mod,
                             const float* __restrict__ w_reg,
                             float* __restrict__ ws) {
    int i = blockIdx.x * blockDim.x + threadIdx.x;
    const int n_wom = CIN * 27 * 9;       // 31104
    const int n_wt  = Cc * KK * Oo;       // 36864
    if (i < n_wom) {
        int k = i % 9;
        int j = (i / 9) % 27;
        int c = i / (9 * 27);
        float v = (j < 18) ? w_off[(j * CIN + c) * 9 + k]
                           : w_mod[((j - 18) * CIN + c) * 9 + k];
        ws[WOM_OFF + i] = v;
    }
    if (i < n_wt) {
        int o = i % Oo;
        int k = (i / Oo) % KK;
        int c = i / (Oo * KK);
        ws[WT_OFF + i] = w_reg[(o * Cc + c) * 9 + k];
    }
}

#define TS   16
#define TP   18
#define LSTR 20

// ---------------------------------------------------------------------------
// conv_partial: 3x3 conv 128->27, channel-split 4 ways over blockIdx.z for
// occupancy (1024 blocks -> 4 blocks/CU -> 16 waves/CU). Each block does 32
// input channels, writes 27 partial sums per pixel.
// ---------------------------------------------------------------------------
#define CPS2 8
__global__ __launch_bounds__(256, 4)
void conv_partial(const float* __restrict__ x, const float* __restrict__ g,
                  const float* __restrict__ ws, float* __restrict__ part) {
    __shared__ float tile[CPS2][TP * LSTR];

    const int tid = threadIdx.x;
    const int tx = tid & 15, ty = tid >> 4;
    const int bx = blockIdx.x, by = blockIdx.y;
    const int b = blockIdx.z >> 2, grp = blockIdx.z & 3;
    const int cbase = grp * 32;
    const int ho = by * TS + ty, wo = bx * TS + tx;
    const int gy0 = by * TS - 1, gx0 = bx * TS - 1;

    const float* wom = ws + WOM_OFF;

    float acc[27];
#pragma unroll
    for (int j = 0; j < 27; j++) acc[j] = 0.f;

    for (int c0 = cbase; c0 < cbase + 32; c0 += CPS2) {
        __syncthreads();
        for (int idx = tid; idx < CPS2 * TP * TP; idx += 256) {
            int plane = idx / (TP * TP);
            int rem = idx - plane * (TP * TP);
            int r = rem / TP, col = rem - r * TP;
            int c = c0 + plane;
            const float* src = (c < Cc) ? (x + ((size_t)(b * Cc + c) << 14))
                                        : (g + ((size_t)(b * Cc + (c - Cc)) << 14));
            int gy = gy0 + r, gx = gx0 + col;
            float v = 0.f;
            if ((unsigned)gy < (unsigned)Hh && (unsigned)gx < (unsigned)Ww)
                v = src[(gy << 7) + gx];
            tile[plane][r * LSTR + col] = v;
        }
        __syncthreads();

#pragma unroll
        for (int p = 0; p < CPS2; p++) {
            int c = c0 + p;
            float v[9];
#pragma unroll
            for (int dy = 0; dy < 3; dy++)
#pragma unroll
                for (int dx = 0; dx < 3; dx++)
                    v[dy * 3 + dx] = tile[p][(ty + dy) * LSTR + (tx + dx)];
            const float* wr = wom + c * 243;   // wave-uniform -> s_load
#pragma unroll
            for (int j = 0; j < 27; j++) {
                float s = 0.f;
#pragma unroll
                for (int k = 0; k < 9; k++) s += wr[j * 9 + k] * v[k];
                acc[j] += s;
            }
        }
    }

    const int pix = (ho << 7) + wo;
    float* pp = part + ((size_t)(grp * Bn + b) * 27) * HW + pix;
#pragma unroll
    for (int j = 0; j < 27; j++) pp[(size_t)j * HW] = acc[j];
}

// ---------------------------------------------------------------------------
// reduce_par: sum 4 partials, add bias, compute sampling coords + modulator.
// ---------------------------------------------------------------------------
__global__ __launch_bounds__(256)
void reduce_par(const float* __restrict__ part,
                const float* __restrict__ b_off, const float* __restrict__ b_mod,
                float* __restrict__ par_out) {
    const int idx = blockIdx.x * 256 + threadIdx.x;   // 0..65535
    const int b = idx >> 14;
    const int pix = idx & (HW - 1);
    const int ho = pix >> 7, wo = pix & 127;

    float a[27];
#pragma unroll
    for (int j = 0; j < 27; j++) a[j] = 0.f;
#pragma unroll
    for (int gidx = 0; gidx < NSPL; gidx++) {
        const float* pp = part + ((size_t)(gidx * Bn + b) * 27) * HW + pix;
#pragma unroll
        for (int j = 0; j < 27; j++) a[j] += pp[(size_t)j * HW];
    }

    float* par = par_out + (size_t)b * NPAR * HW + pix;
#pragma unroll
    for (int k = 0; k < 9; k++) {
        float py = a[2 * k] + b_off[2 * k] + (float)(k / 3) + (float)(ho - 1);
        float px = a[2 * k + 1] + b_off[2 * k + 1] + (float)(k % 3) + (float)(wo - 1);
        float mv = a[18 + k] + b_mod[k];
        float m = 2.f / (1.f + __expf(-mv));
        par[(size_t)k * HW]        = py;
        par[(size_t)(9 + k) * HW]  = px;
        par[(size_t)(18 + k) * HW] = m;
    }
}

// ---------------------------------------------------------------------------
// Fallback conv (round-1, passing): used only if ws_size is too small.
// ---------------------------------------------------------------------------
#define CPS  4
__global__ __launch_bounds__(256)
void conv_offmod(const float* __restrict__ x, const float* __restrict__ g,
                 const float* __restrict__ b_off, const float* __restrict__ b_mod,
                 float* __restrict__ ws) {
    __shared__ float tile[CPS][TP * LSTR];

    const int tid = threadIdx.x;
    const int tx = tid & 15, ty = tid >> 4;
    const int bx = blockIdx.x, by = blockIdx.y, b = blockIdx.z;
    const int ho = by * TS + ty, wo = bx * TS + tx;
    const int gy0 = by * TS - 1, gx0 = bx * TS - 1;

    const float* wom = ws + WOM_OFF;

    float acc[27];
#pragma unroll
    for (int j = 0; j < 27; j++) acc[j] = 0.f;

    for (int c0 = 0; c0 < CIN; c0 += CPS) {
        __syncthreads();
        for (int idx = tid; idx < CPS * TP * TP; idx += 256) {
            int plane = idx / (TP * TP);
            int rem = idx - plane * (TP * TP);
            int r = rem / TP, col = rem - r * TP;
            int c = c0 + plane;
            const float* src = (c < Cc) ? (x + ((size_t)(b * Cc + c) << 14))
                                        : (g + ((size_t)(b * Cc + (c - Cc)) << 14));
            int gy = gy0 + r, gx = gx0 + col;
            float v = 0.f;
            if ((unsigned)gy < (unsigned)Hh && (unsigned)gx < (unsigned)Ww)
                v = src[(gy << 7) + gx];
            tile[plane][r * LSTR + col] = v;
        }
        __syncthreads();

        for (int p = 0; p < CPS; p++) {
            int c = c0 + p;
            float v[9];
#pragma unroll
            for (int dy = 0; dy < 3; dy++)
#pragma unroll
                for (int dx = 0; dx < 3; dx++)
                    v[dy * 3 + dx] = tile[p][(ty + dy) * LSTR + (tx + dx)];
            const float* wr = wom + c * 243;
#pragma unroll
            for (int j = 0; j < 27; j++) {
                float s = 0.f;
#pragma unroll
                for (int k = 0; k < 9; k++) s += wr[j * 9 + k] * v[k];
                acc[j] += s;
            }
        }
    }

    const int pix = (ho << 7) + wo;
    float* par = ws + PAR1_OFF + (size_t)b * NPAR * HW;
#pragma unroll
    for (int k = 0; k < 9; k++) {
        float oy = acc[2 * k] + b_off[2 * k];
        float ox = acc[2 * k + 1] + b_off[2 * k + 1];
        float py = oy + (float)(k / 3) + (float)(ho - 1);
        float px = ox + (float)(k % 3) + (float)(wo - 1);
        float mv = acc[18 + k] + b_mod[k];
        float m = 2.f / (1.f + __expf(-mv));
        par[(size_t)k * HW + pix]        = py;
        par[(size_t)(9 + k) * HW + pix]  = px;
        par[(size_t)(18 + k) * HW + pix] = m;
    }
}

// ---------------------------------------------------------------------------
// deform_gemm2: 256 threads = 4 channel-splits x 64 pixels (16x4 tile).
// Each thread: 16 channels x 9 taps, bilinear gather once, 64-output FMA
// with wave-uniform scalar-loaded weights. LDS reduction across splits.
// ---------------------------------------------------------------------------
__global__ __launch_bounds__(256, 4)
void deform_gemm2(const float* __restrict__ x, const float* __restrict__ ws_,
                  const float* __restrict__ par_base, float* __restrict__ out) {
    __shared__ float red[64][65];

    const int tid = threadIdx.x;
    const int r = tid >> 6, p = tid & 63;
    const int b = blockIdx.z;
    const int ho = blockIdx.y * 4 + (p >> 4);
    const int wo = blockIdx.x * 16 + (p & 15);
    const int pix = (ho << 7) + wo;

    const float* par = par_base + (size_t)b * NPAR * HW + pix;
    const float* wT  = ws_ + WT_OFF;
    const int cbase = r * 16;
    const float* xb = x + ((size_t)(b * Cc + cbase) << 14);

    float acc[64];
#pragma unroll
    for (int o = 0; o < 64; o++) acc[o] = 0.f;

    for (int k = 0; k < 9; k++) {
        float py = par[(size_t)k * HW];
        float px = par[(size_t)(9 + k) * HW];
        float m  = par[(size_t)(18 + k) * HW];
        float fy = floorf(py), fx = floorf(px);
        int y0 = (int)fy, x0 = (int)fx;
        int y1 = y0 + 1, x1 = x0 + 1;
        float wy1 = py - fy, wx1 = px - fx;
        float wy0 = 1.f - wy1, wx0 = 1.f - wx1;
        bool vy0 = (unsigned)y0 < (unsigned)Hh, vy1 = (unsigned)y1 < (unsigned)Hh;
        bool vx0 = (unsigned)x0 < (unsigned)Ww, vx1 = (unsigned)x1 < (unsigned)Ww;
        int cy0 = min(max(y0, 0), Hh - 1), cy1 = min(max(y1, 0), Hh - 1);
        int cx0 = min(max(x0, 0), Ww - 1), cx1 = min(max(x1, 0), Ww - 1);
        float w00 = (vy0 && vx0) ? wy0 * wx0 * m : 0.f;
        float w01 = (vy0 && vx1) ? wy0 * wx1 * m : 0.f;
        float w10 = (vy1 && vx0) ? wy1 * wx0 * m : 0.f;
        float w11 = (vy1 && vx1) ? wy1 * wx1 * m : 0.f;
        int i00 = (cy0 << 7) + cx0, i01 = (cy0 << 7) + cx1;
        int i10 = (cy1 << 7) + cx0, i11 = (cy1 << 7) + cx1;

        const float* xp = xb;
#pragma unroll
        for (int i = 0; i < 16; i++, xp += HW) {
            float val = w00 * xp[i00] + w01 * xp[i01]
                      + w10 * xp[i10] + w11 * xp[i11];
            const float* wr = wT + (((size_t)(cbase + i) * 9 + k) << 6); // uniform
#pragma unroll
            for (int o = 0; o < 64; o++) acc[o] += wr[o] * val;
        }
    }

    // Reduce splits 1..3 into split 0 via LDS (padded, conflict-free)
    for (int rr = 1; rr <= 3; rr++) {
        if (r == rr) {
#pragma unroll
            for (int o = 0; o < 64; o++) red[p][o] = acc[o];
        }
        __syncthreads();
        if (r == 0) {
#pragma unroll
            for (int o = 0; o < 64; o++) acc[o] += red[p][o];
        }
        __syncthreads();
    }

    if (r == 0) {
        float* op = out + ((size_t)(b * Oo) << 14) + pix;
#pragma unroll
        for (int o = 0; o < 64; o++) op[(size_t)o << 14] = acc[o];
    }
}

// ---------------------------------------------------------------------------
extern "C" void kernel_launch(void* const* d_in, const int* in_sizes, int n_in,
                              void* d_out, int out_size, void* d_ws, size_t ws_size,
                              hipStream_t stream) {
    const float* x     = (const float*)d_in[0];
    const float* guide = (const float*)d_in[1];
    const float* w_off = (const float*)d_in[2];
    const float* b_off = (const float*)d_in[3];
    const float* w_mod = (const float*)d_in[4];
    const float* b_mod = (const float*)d_in[5];
    const float* w_reg = (const float*)d_in[6];
    float* out = (float*)d_out;
    float* ws  = (float*)d_ws;

    hipLaunchKernelGGL(prep_weights, dim3((Cc * KK * Oo + 255) / 256), dim3(256),
                       0, stream, w_off, w_mod, w_reg, ws);

    const bool big = ws_size >= (size_t)WS_NEED_FLOATS * sizeof(float);
    const float* par_base;
    if (big) {
        hipLaunchKernelGGL(conv_partial, dim3(Ww / TS, Hh / TS, Bn * NSPL), dim3(256),
                           0, stream, x, guide, ws, ws + PART_OFF);
        hipLaunchKernelGGL(reduce_par, dim3(Bn * HW / 256), dim3(256),
                           0, stream, ws + PART_OFF, b_off, b_mod, ws + PAR2_OFF);
        par_base = ws + PAR2_OFF;
    } else {
        hipLaunchKernelGGL(conv_offmod, dim3(Ww / TS, Hh / TS, Bn), dim3(256),
                           0, stream, x, guide, b_off, b_mod, ws);
        par_base = ws + PAR1_OFF;
    }

    hipLaunchKernelGGL(deform_gemm2, dim3(Ww / 16, Hh / 4, Bn), dim3(256),
                       0, stream, x, ws, par_base, out);
}

// Round 3
// 375.319 us; speedup vs baseline: 2.1479x; 2.1303x over previous
//
#include <hip/hip_runtime.h>
#include <math.h>

// Problem constants
#define Bn   4
#define Cc   64
#define Hh   128
#define Ww   128
#define Oo   64
#define HW   (Hh * Ww)          // 16384
#define CIN  128                // 2*C
#define KK   9
#define NPAR 27                 // py[9] px[9] m[9]
#define NSPL 4                  // conv channel-split groups

// Workspace layout (float offsets)
#define WOM_OFF  0                         // [CIN][27][9]  = 31104 floats
#define WT_OFF   (CIN * 27 * 9)            // [C][KK][Oo]   = 36864 floats
#define PAR1_OFF (WT_OFF + Cc * KK * Oo)   // fallback par [B][27][HW]
#define PART_OFF PAR1_OFF                  // big path: partials [4][B][27][HW]
#define PAR2_OFF (PART_OFF + NSPL * Bn * NPAR * HW)
#define WS_NEED_FLOATS (PAR2_OFF + Bn * NPAR * HW)

// ---------------------------------------------------------------------------
// Prepass: reorder weights for wave-uniform (scalar-load) access in hot loops.
// ---------------------------------------------------------------------------
__global__ void prep_weights(const float* __restrict__ w_off,
                             const float* __restrict__ w_mod,
                             const float* __restrict__ w_reg,
                             float* __restrict__ ws) {
    int i = blockIdx.x * blockDim.x + threadIdx.x;
    const int n_wom = CIN * 27 * 9;       // 31104
    const int n_wt  = Cc * KK * Oo;       // 36864
    if (i < n_wom) {
        int k = i % 9;
        int j = (i / 9) % 27;
        int c = i / (9 * 27);
        float v = (j < 18) ? w_off[(j * CIN + c) * 9 + k]
                           : w_mod[((j - 18) * CIN + c) * 9 + k];
        ws[WOM_OFF + i] = v;
    }
    if (i < n_wt) {
        int o = i % Oo;
        int k = (i / Oo) % KK;
        int c = i / (Oo * KK);
        ws[WT_OFF + i] = w_reg[(o * Cc + c) * 9 + k];
    }
}

#define TS   16
#define TP   18
#define LSTR 20

// ---------------------------------------------------------------------------
// conv_partial: 3x3 conv 128->27, channel-split 4 ways over blockIdx.z.
// ---------------------------------------------------------------------------
#define CPS2 8
__global__ __launch_bounds__(256, 4)
void conv_partial(const float* __restrict__ x, const float* __restrict__ g,
                  const float* __restrict__ ws, float* __restrict__ part) {
    __shared__ float tile[CPS2][TP * LSTR];

    const int tid = threadIdx.x;
    const int tx = tid & 15, ty = tid >> 4;
    const int bx = blockIdx.x, by = blockIdx.y;
    const int b = blockIdx.z >> 2, grp = blockIdx.z & 3;
    const int cbase = grp * 32;
    const int ho = by * TS + ty, wo = bx * TS + tx;
    const int gy0 = by * TS - 1, gx0 = bx * TS - 1;

    const float* wom = ws + WOM_OFF;

    float acc[27];
#pragma unroll
    for (int j = 0; j < 27; j++) acc[j] = 0.f;

    for (int c0 = cbase; c0 < cbase + 32; c0 += CPS2) {
        __syncthreads();
        for (int idx = tid; idx < CPS2 * TP * TP; idx += 256) {
            int plane = idx / (TP * TP);
            int rem = idx - plane * (TP * TP);
            int r = rem / TP, col = rem - r * TP;
            int c = c0 + plane;
            const float* src = (c < Cc) ? (x + ((size_t)(b * Cc + c) << 14))
                                        : (g + ((size_t)(b * Cc + (c - Cc)) << 14));
            int gy = gy0 + r, gx = gx0 + col;
            float v = 0.f;
            if ((unsigned)gy < (unsigned)Hh && (unsigned)gx < (unsigned)Ww)
                v = src[(gy << 7) + gx];
            tile[plane][r * LSTR + col] = v;
        }
        __syncthreads();

#pragma unroll
        for (int p = 0; p < CPS2; p++) {
            int c = c0 + p;
            float v[9];
#pragma unroll
            for (int dy = 0; dy < 3; dy++)
#pragma unroll
                for (int dx = 0; dx < 3; dx++)
                    v[dy * 3 + dx] = tile[p][(ty + dy) * LSTR + (tx + dx)];
            const float* wr = wom + c * 243;   // wave-uniform -> s_load
#pragma unroll
            for (int j = 0; j < 27; j++) {
                float s = 0.f;
#pragma unroll
                for (int k = 0; k < 9; k++) s += wr[j * 9 + k] * v[k];
                acc[j] += s;
            }
        }
    }

    const int pix = (ho << 7) + wo;
    float* pp = part + ((size_t)(grp * Bn + b) * 27) * HW + pix;
#pragma unroll
    for (int j = 0; j < 27; j++) pp[(size_t)j * HW] = acc[j];
}

// ---------------------------------------------------------------------------
// reduce_par: sum 4 partials, add bias, compute sampling coords + modulator.
// ---------------------------------------------------------------------------
__global__ __launch_bounds__(256)
void reduce_par(const float* __restrict__ part,
                const float* __restrict__ b_off, const float* __restrict__ b_mod,
                float* __restrict__ par_out) {
    const int idx = blockIdx.x * 256 + threadIdx.x;   // 0..65535
    const int b = idx >> 14;
    const int pix = idx & (HW - 1);
    const int ho = pix >> 7, wo = pix & 127;

    float a[27];
#pragma unroll
    for (int j = 0; j < 27; j++) a[j] = 0.f;
#pragma unroll
    for (int gidx = 0; gidx < NSPL; gidx++) {
        const float* pp = part + ((size_t)(gidx * Bn + b) * 27) * HW + pix;
#pragma unroll
        for (int j = 0; j < 27; j++) a[j] += pp[(size_t)j * HW];
    }

    float* par = par_out + (size_t)b * NPAR * HW + pix;
#pragma unroll
    for (int k = 0; k < 9; k++) {
        float py = a[2 * k] + b_off[2 * k] + (float)(k / 3) + (float)(ho - 1);
        float px = a[2 * k + 1] + b_off[2 * k + 1] + (float)(k % 3) + (float)(wo - 1);
        float mv = a[18 + k] + b_mod[k];
        float m = 2.f / (1.f + __expf(-mv));
        par[(size_t)k * HW]        = py;
        par[(size_t)(9 + k) * HW]  = px;
        par[(size_t)(18 + k) * HW] = m;
    }
}

// ---------------------------------------------------------------------------
// Fallback conv (round-1, passing): used only if ws_size is too small.
// ---------------------------------------------------------------------------
#define CPS  4
__global__ __launch_bounds__(256)
void conv_offmod(const float* __restrict__ x, const float* __restrict__ g,
                 const float* __restrict__ b_off, const float* __restrict__ b_mod,
                 float* __restrict__ ws) {
    __shared__ float tile[CPS][TP * LSTR];

    const int tid = threadIdx.x;
    const int tx = tid & 15, ty = tid >> 4;
    const int bx = blockIdx.x, by = blockIdx.y, b = blockIdx.z;
    const int ho = by * TS + ty, wo = bx * TS + tx;
    const int gy0 = by * TS - 1, gx0 = bx * TS - 1;

    const float* wom = ws + WOM_OFF;

    float acc[27];
#pragma unroll
    for (int j = 0; j < 27; j++) acc[j] = 0.f;

    for (int c0 = 0; c0 < CIN; c0 += CPS) {
        __syncthreads();
        for (int idx = tid; idx < CPS * TP * TP; idx += 256) {
            int plane = idx / (TP * TP);
            int rem = idx - plane * (TP * TP);
            int r = rem / TP, col = rem - r * TP;
            int c = c0 + plane;
            const float* src = (c < Cc) ? (x + ((size_t)(b * Cc + c) << 14))
                                        : (g + ((size_t)(b * Cc + (c - Cc)) << 14));
            int gy = gy0 + r, gx = gx0 + col;
            float v = 0.f;
            if ((unsigned)gy < (unsigned)Hh && (unsigned)gx < (unsigned)Ww)
                v = src[(gy << 7) + gx];
            tile[plane][r * LSTR + col] = v;
        }
        __syncthreads();

        for (int p = 0; p < CPS; p++) {
            int c = c0 + p;
            float v[9];
#pragma unroll
            for (int dy = 0; dy < 3; dy++)
#pragma unroll
                for (int dx = 0; dx < 3; dx++)
                    v[dy * 3 + dx] = tile[p][(ty + dy) * LSTR + (tx + dx)];
            const float* wr = wom + c * 243;
#pragma unroll
            for (int j = 0; j < 27; j++) {
                float s = 0.f;
#pragma unroll
                for (int k = 0; k < 9; k++) s += wr[j * 9 + k] * v[k];
                acc[j] += s;
            }
        }
    }

    const int pix = (ho << 7) + wo;
    float* par = ws + PAR1_OFF + (size_t)b * NPAR * HW;
#pragma unroll
    for (int k = 0; k < 9; k++) {
        float oy = acc[2 * k] + b_off[2 * k];
        float ox = acc[2 * k + 1] + b_off[2 * k + 1];
        float py = oy + (float)(k / 3) + (float)(ho - 1);
        float px = ox + (float)(k % 3) + (float)(wo - 1);
        float mv = acc[18 + k] + b_mod[k];
        float m = 2.f / (1.f + __expf(-mv));
        par[(size_t)k * HW + pix]        = py;
        par[(size_t)(9 + k) * HW + pix]  = px;
        par[(size_t)(18 + k) * HW + pix] = m;
    }
}

// ---------------------------------------------------------------------------
// deform_tiled: LDS-staged tile GEMM. Block = 64 pixels (16x4), 256 threads
// = 4 waves. Stage A: bilinear params (9 taps x 64 px) -> LDS. K-loop over
// 8 chunks of 72 K-values (8 ch x 9 taps): phase 1 computes V[72][64] tile
// in LDS (each sampled value gathered exactly once); phase 2: wave og owns
// output channels og*16..+15 (scalarized -> weights via s_load), acc[16]
// per thread (no spill), V via stride-1 ds_read_b32.
// ---------------------------------------------------------------------------
__global__ __launch_bounds__(256, 4)
void deform_tiled(const float* __restrict__ x, const float* __restrict__ ws_,
                  const float* __restrict__ par_base, float* __restrict__ out) {
    __shared__ int4   sIdx[9 * 64];
    __shared__ float4 sWt [9 * 64];
    __shared__ float  V[72 * 64];

    const int tid = threadIdx.x;
    const int l = tid & 63;                 // pixel lane
    const int og = tid >> 6;                // wave id = output group
    const int og_s = __builtin_amdgcn_readfirstlane(og);
    const int b = blockIdx.z;
    const int ho = blockIdx.y * 4 + (l >> 4);
    const int wo = blockIdx.x * 16 + (l & 15);
    const int pix = (ho << 7) + wo;

    const float* par = par_base + (size_t)b * NPAR * HW;
    const float* wT  = ws_ + WT_OFF;
    const float* xb  = x + ((size_t)(b * Cc) << 14);

    // Stage A: bilinear params for 9 taps x 64 pixels
    for (int s = tid; s < 9 * 64; s += 256) {
        int k = s >> 6;
        int sl = s & 63;
        int sho = blockIdx.y * 4 + (sl >> 4);
        int swo = blockIdx.x * 16 + (sl & 15);
        int spix = (sho << 7) + swo;
        float py = par[(size_t)k * HW + spix];
        float px = par[(size_t)(9 + k) * HW + spix];
        float m  = par[(size_t)(18 + k) * HW + spix];
        float fy = floorf(py), fx = floorf(px);
        int y0 = (int)fy, x0 = (int)fx;
        int y1 = y0 + 1, x1 = x0 + 1;
        float wy1 = py - fy, wx1 = px - fx;
        float wy0 = 1.f - wy1, wx0 = 1.f - wx1;
        bool vy0 = (unsigned)y0 < (unsigned)Hh, vy1 = (unsigned)y1 < (unsigned)Hh;
        bool vx0 = (unsigned)x0 < (unsigned)Ww, vx1 = (unsigned)x1 < (unsigned)Ww;
        int cy0 = min(max(y0, 0), Hh - 1), cy1 = min(max(y1, 0), Hh - 1);
        int cx0 = min(max(x0, 0), Ww - 1), cx1 = min(max(x1, 0), Ww - 1);
        sIdx[s] = make_int4((cy0 << 7) + cx0, (cy0 << 7) + cx1,
                            (cy1 << 7) + cx0, (cy1 << 7) + cx1);
        sWt[s] = make_float4((vy0 && vx0) ? wy0 * wx0 * m : 0.f,
                             (vy0 && vx1) ? wy0 * wx1 * m : 0.f,
                             (vy1 && vx0) ? wy1 * wx0 * m : 0.f,
                             (vy1 && vx1) ? wy1 * wx1 * m : 0.f);
    }

    float acc[16];
#pragma unroll
    for (int i = 0; i < 16; i++) acc[i] = 0.f;

    for (int cc = 0; cc < 8; cc++) {
        __syncthreads();   // protect V (prev phase-2 reads done; stage A on cc=0)
        // Phase 1: V[kk][l], kk = og + 4j, j=0..17 (exactly 72 rows)
#pragma unroll
        for (int j = 0; j < 18; j++) {
            int kk = og + (j << 2);
            int cl = kk / 9;
            int k = kk - 9 * cl;
            int4   id = sIdx[(k << 6) + l];
            float4 w  = sWt [(k << 6) + l];
            const float* xq = xb + ((size_t)((cc << 3) + cl) << 14);
            float val = w.x * xq[id.x] + w.y * xq[id.y]
                      + w.z * xq[id.z] + w.w * xq[id.w];
            V[(kk << 6) + l] = val;
        }
        __syncthreads();
        // Phase 2: weight row index = c*9+k = cc*72 + kk (no division)
#pragma unroll 4
        for (int kk = 0; kk < 72; kk++) {
            const float* wr = wT + ((size_t)(cc * 72 + kk) << 6) + (og_s << 4);
            float val = V[(kk << 6) + l];
#pragma unroll
            for (int i = 0; i < 16; i++) acc[i] += wr[i] * val;
        }
    }

    float* op = out + ((size_t)(b * Oo + (og_s << 4)) << 14) + pix;
#pragma unroll
    for (int i = 0; i < 16; i++) op[(size_t)i << 14] = acc[i];
}

// ---------------------------------------------------------------------------
extern "C" void kernel_launch(void* const* d_in, const int* in_sizes, int n_in,
                              void* d_out, int out_size, void* d_ws, size_t ws_size,
                              hipStream_t stream) {
    const float* x     = (const float*)d_in[0];
    const float* guide = (const float*)d_in[1];
    const float* w_off = (const float*)d_in[2];
    const float* b_off = (const float*)d_in[3];
    const float* w_mod = (const float*)d_in[4];
    const float* b_mod = (const float*)d_in[5];
    const float* w_reg = (const float*)d_in[6];
    float* out = (float*)d_out;
    float* ws  = (float*)d_ws;

    hipLaunchKernelGGL(prep_weights, dim3((Cc * KK * Oo + 255) / 256), dim3(256),
                       0, stream, w_off, w_mod, w_reg, ws);

    const bool big = ws_size >= (size_t)WS_NEED_FLOATS * sizeof(float);
    const float* par_base;
    if (big) {
        hipLaunchKernelGGL(conv_partial, dim3(Ww / TS, Hh / TS, Bn * NSPL), dim3(256),
                           0, stream, x, guide, ws, ws + PART_OFF);
        hipLaunchKernelGGL(reduce_par, dim3(Bn * HW / 256), dim3(256),
                           0, stream, ws + PART_OFF, b_off, b_mod, ws + PAR2_OFF);
        par_base = ws + PAR2_OFF;
    } else {
        hipLaunchKernelGGL(conv_offmod, dim3(Ww / TS, Hh / TS, Bn), dim3(256),
                           0, stream, x, guide, b_off, b_mod, ws);
        par_base = ws + PAR1_OFF;
    }

    hipLaunchKernelGGL(deform_tiled, dim3(Ww / 16, Hh / 4, Bn), dim3(256),
                       0, stream, x, ws, par_base, out);
}

// Round 4
// 339.047 us; speedup vs baseline: 2.3777x; 1.1070x over previous
//
#include <hip/hip_runtime.h>
#include <math.h>

// Problem constants
#define Bn   4
#define Cc   64
#define Hh   128
#define Ww   128
#define Oo   64
#define HW   16384
#define CIN  128
#define KK   9
#define NPAR 27
#define NSPL 4

// Workspace layout (float offsets)
#define WOM_OFF  0                          // [CIN][27][9] = 31104 floats
#define WB_OFF   (CIN * 27 * 9)             // bf16 W[64][576] = 36864 shorts = 18432 float slots
#define PAR1_OFF (WB_OFF + (Oo * Cc * KK) / 2)
#define PART_OFF PAR1_OFF                   // big path: partials [4][B][27][HW]
#define PAR2_OFF (PART_OFF + NSPL * Bn * NPAR * HW)
#define WS_NEED_FLOATS (PAR2_OFF + Bn * NPAR * HW)

typedef __attribute__((ext_vector_type(8))) short bf16x8;
typedef __attribute__((ext_vector_type(4))) float f32x4;

__device__ __forceinline__ short f2bf(float f) {
    unsigned u = __builtin_bit_cast(unsigned, f);
    u += 0x7FFFu + ((u >> 16) & 1u);        // RNE
    return (short)(u >> 16);
}

// ---------------------------------------------------------------------------
// Prepass: reorder conv weights (wave-uniform scalar access) + bf16 W for MFMA.
//   wom[c][j][k];  wb[o][c*9+k] (bf16)
// ---------------------------------------------------------------------------
__global__ void prep_weights(const float* __restrict__ w_off,
                             const float* __restrict__ w_mod,
                             const float* __restrict__ w_reg,
                             float* __restrict__ ws) {
    int i = blockIdx.x * blockDim.x + threadIdx.x;
    const int n_wom = CIN * 27 * 9;       // 31104
    const int n_wb  = Oo * Cc * KK;       // 36864
    if (i < n_wom) {
        int k = i % 9;
        int j = (i / 9) % 27;
        int c = i / (9 * 27);
        float v = (j < 18) ? w_off[(j * CIN + c) * 9 + k]
                           : w_mod[((j - 18) * CIN + c) * 9 + k];
        ws[WOM_OFF + i] = v;
    }
    if (i < n_wb) {
        int kkg = i % 576;                // c*9+k
        int o = i / 576;
        short* wb = (short*)(ws + WB_OFF);
        wb[o * 576 + kkg] = f2bf(w_reg[o * 576 + kkg]);  // w_reg is [O][C][9] = [o][kkg]
    }
}

#define TS   16
#define TP   18
#define LSTR 20

// ---------------------------------------------------------------------------
// conv_partial: 3x3 conv 128->27, channel-split 4 ways (unchanged from R3).
// ---------------------------------------------------------------------------
#define CPS2 8
__global__ __launch_bounds__(256, 4)
void conv_partial(const float* __restrict__ x, const float* __restrict__ g,
                  const float* __restrict__ ws, float* __restrict__ part) {
    __shared__ float tile[CPS2][TP * LSTR];

    const int tid = threadIdx.x;
    const int tx = tid & 15, ty = tid >> 4;
    const int bx = blockIdx.x, by = blockIdx.y;
    const int b = blockIdx.z >> 2, grp = blockIdx.z & 3;
    const int cbase = grp * 32;
    const int ho = by * TS + ty, wo = bx * TS + tx;
    const int gy0 = by * TS - 1, gx0 = bx * TS - 1;

    const float* wom = ws + WOM_OFF;

    float acc[27];
#pragma unroll
    for (int j = 0; j < 27; j++) acc[j] = 0.f;

    for (int c0 = cbase; c0 < cbase + 32; c0 += CPS2) {
        __syncthreads();
        for (int idx = tid; idx < CPS2 * TP * TP; idx += 256) {
            int plane = idx / (TP * TP);
            int rem = idx - plane * (TP * TP);
            int r = rem / TP, col = rem - r * TP;
            int c = c0 + plane;
            const float* src = (c < Cc) ? (x + ((size_t)(b * Cc + c) << 14))
                                        : (g + ((size_t)(b * Cc + (c - Cc)) << 14));
            int gy = gy0 + r, gx = gx0 + col;
            float v = 0.f;
            if ((unsigned)gy < (unsigned)Hh && (unsigned)gx < (unsigned)Ww)
                v = src[(gy << 7) + gx];
            tile[plane][r * LSTR + col] = v;
        }
        __syncthreads();

#pragma unroll
        for (int p = 0; p < CPS2; p++) {
            int c = c0 + p;
            float v[9];
#pragma unroll
            for (int dy = 0; dy < 3; dy++)
#pragma unroll
                for (int dx = 0; dx < 3; dx++)
                    v[dy * 3 + dx] = tile[p][(ty + dy) * LSTR + (tx + dx)];
            const float* wr = wom + c * 243;   // wave-uniform -> s_load
#pragma unroll
            for (int j = 0; j < 27; j++) {
                float s = 0.f;
#pragma unroll
                for (int k = 0; k < 9; k++) s += wr[j * 9 + k] * v[k];
                acc[j] += s;
            }
        }
    }

    const int pix = (ho << 7) + wo;
    float* pp = part + ((size_t)(grp * Bn + b) * 27) * HW + pix;
#pragma unroll
    for (int j = 0; j < 27; j++) pp[(size_t)j * HW] = acc[j];
}

// ---------------------------------------------------------------------------
// reduce_par: sum partials, add bias, compute sampling coords + modulator.
// ---------------------------------------------------------------------------
__global__ __launch_bounds__(256)
void reduce_par(const float* __restrict__ part,
                const float* __restrict__ b_off, const float* __restrict__ b_mod,
                float* __restrict__ par_out) {
    const int idx = blockIdx.x * 256 + threadIdx.x;
    const int b = idx >> 14;
    const int pix = idx & (HW - 1);
    const int ho = pix >> 7, wo = pix & 127;

    float a[27];
#pragma unroll
    for (int j = 0; j < 27; j++) a[j] = 0.f;
#pragma unroll
    for (int gidx = 0; gidx < NSPL; gidx++) {
        const float* pp = part + ((size_t)(gidx * Bn + b) * 27) * HW + pix;
#pragma unroll
        for (int j = 0; j < 27; j++) a[j] += pp[(size_t)j * HW];
    }

    float* par = par_out + (size_t)b * NPAR * HW + pix;
#pragma unroll
    for (int k = 0; k < 9; k++) {
        float py = a[2 * k] + b_off[2 * k] + (float)(k / 3) + (float)(ho - 1);
        float px = a[2 * k + 1] + b_off[2 * k + 1] + (float)(k % 3) + (float)(wo - 1);
        float mv = a[18 + k] + b_mod[k];
        float m = 2.f / (1.f + __expf(-mv));
        par[(size_t)k * HW]        = py;
        par[(size_t)(9 + k) * HW]  = px;
        par[(size_t)(18 + k) * HW] = m;
    }
}

// ---------------------------------------------------------------------------
// Fallback conv (round-1, passing): used only if ws_size is too small.
// ---------------------------------------------------------------------------
#define CPS  4
__global__ __launch_bounds__(256)
void conv_offmod(const float* __restrict__ x, const float* __restrict__ g,
                 const float* __restrict__ b_off, const float* __restrict__ b_mod,
                 float* __restrict__ ws) {
    __shared__ float tile[CPS][TP * LSTR];

    const int tid = threadIdx.x;
    const int tx = tid & 15, ty = tid >> 4;
    const int bx = blockIdx.x, by = blockIdx.y, b = blockIdx.z;
    const int ho = by * TS + ty, wo = bx * TS + tx;
    const int gy0 = by * TS - 1, gx0 = bx * TS - 1;

    const float* wom = ws + WOM_OFF;

    float acc[27];
#pragma unroll
    for (int j = 0; j < 27; j++) acc[j] = 0.f;

    for (int c0 = 0; c0 < CIN; c0 += CPS) {
        __syncthreads();
        for (int idx = tid; idx < CPS * TP * TP; idx += 256) {
            int plane = idx / (TP * TP);
            int rem = idx - plane * (TP * TP);
            int r = rem / TP, col = rem - r * TP;
            int c = c0 + plane;
            const float* src = (c < Cc) ? (x + ((size_t)(b * Cc + c) << 14))
                                        : (g + ((size_t)(b * Cc + (c - Cc)) << 14));
            int gy = gy0 + r, gx = gx0 + col;
            float v = 0.f;
            if ((unsigned)gy < (unsigned)Hh && (unsigned)gx < (unsigned)Ww)
                v = src[(gy << 7) + gx];
            tile[plane][r * LSTR + col] = v;
        }
        __syncthreads();

        for (int p = 0; p < CPS; p++) {
            int c = c0 + p;
            float v[9];
#pragma unroll
            for (int dy = 0; dy < 3; dy++)
#pragma unroll
                for (int dx = 0; dx < 3; dx++)
                    v[dy * 3 + dx] = tile[p][(ty + dy) * LSTR + (tx + dx)];
            const float* wr = wom + c * 243;
#pragma unroll
            for (int j = 0; j < 27; j++) {
                float s = 0.f;
#pragma unroll
                for (int k = 0; k < 9; k++) s += wr[j * 9 + k] * v[k];
                acc[j] += s;
            }
        }
    }

    const int pix = (ho << 7) + wo;
    float* par = ws + PAR1_OFF + (size_t)b * NPAR * HW;
#pragma unroll
    for (int k = 0; k < 9; k++) {
        float py = acc[2 * k] + b_off[2 * k] + (float)(k / 3) + (float)(ho - 1);
        float px = acc[2 * k + 1] + b_off[2 * k + 1] + (float)(k % 3) + (float)(wo - 1);
        float mv = acc[18 + k] + b_mod[k];
        float m = 2.f / (1.f + __expf(-mv));
        par[(size_t)k * HW + pix]        = py;
        par[(size_t)(9 + k) * HW + pix]  = px;
        par[(size_t)(18 + k) * HW + pix] = m;
    }
}

// ---------------------------------------------------------------------------
// deform_mfma: per 64-px tile (16x4), C[64o][64px] = W[64][576] x V[576][64]
// via mfma_f32_16x16x32_bf16. K split into 9 chunks of 64 (8 ch x 9 taps
// blocks, kkg = c*9+k). Phase 1: fp32 bilinear gather -> bf16 V_T[px][kk]
// in LDS; (c,k) wave-uniform per step -> scalar tap/plane addressing.
// Phase 2: wave r computes out rows [16r,16r+16): A from global bf16 W
// (L1-hot 72KB), B via ds_read_b128, fp32 accum.
// Layouts (m89/m120-verified): A[m=lane&15][k=quad*8+j],
// B[k=quad*8+j][n=lane&15], D[row=quad*4+reg][col=lane&15].
// ---------------------------------------------------------------------------
#define VSTR 72   // V_T row stride in bf16 (64 + 8 pad)

__global__ __launch_bounds__(256, 4)
void deform_mfma(const float* __restrict__ x, const float* __restrict__ ws_,
                 const float* __restrict__ par_base, float* __restrict__ out) {
    __shared__ int4   sIdx[576];
    __shared__ float4 sWt [576];
    __shared__ __align__(16) short V[64 * VSTR];

    const int tid = threadIdx.x;
    const int l = tid & 63;
    const int lm = l & 15, quad = l >> 4;
    const int rs = __builtin_amdgcn_readfirstlane(tid >> 6);   // wave id
    const int b = blockIdx.z;

    const float* par = par_base + (size_t)b * NPAR * HW;
    const short* wb  = (const short*)(ws_ + WB_OFF);
    const float* xb  = x + ((size_t)(b * Cc) << 14);

    // Stage A: bilinear params for 9 taps x 64 pixels
    for (int s = tid; s < 576; s += 256) {
        int k = s >> 6;
        int sl = s & 63;
        int sho = blockIdx.y * 4 + (sl >> 4);
        int swo = blockIdx.x * 16 + (sl & 15);
        int spix = (sho << 7) + swo;
        float py = par[(size_t)k * HW + spix];
        float px = par[(size_t)(9 + k) * HW + spix];
        float m  = par[(size_t)(18 + k) * HW + spix];
        float fy = floorf(py), fx = floorf(px);
        int y0 = (int)fy, x0 = (int)fx;
        int y1 = y0 + 1, x1 = x0 + 1;
        float wy1 = py - fy, wx1 = px - fx;
        float wy0 = 1.f - wy1, wx0 = 1.f - wx1;
        bool vy0 = (unsigned)y0 < (unsigned)Hh, vy1 = (unsigned)y1 < (unsigned)Hh;
        bool vx0 = (unsigned)x0 < (unsigned)Ww, vx1 = (unsigned)x1 < (unsigned)Ww;
        int cy0 = min(max(y0, 0), Hh - 1), cy1 = min(max(y1, 0), Hh - 1);
        int cx0 = min(max(x0, 0), Ww - 1), cx1 = min(max(x1, 0), Ww - 1);
        sIdx[s] = make_int4((cy0 << 7) + cx0, (cy0 << 7) + cx1,
                            (cy1 << 7) + cx0, (cy1 << 7) + cx1);
        sWt[s] = make_float4((vy0 && vx0) ? wy0 * wx0 * m : 0.f,
                             (vy0 && vx1) ? wy0 * wx1 * m : 0.f,
                             (vy1 && vx0) ? wy1 * wx0 * m : 0.f,
                             (vy1 && vx1) ? wy1 * wx1 * m : 0.f);
    }

    f32x4 acc[4];
#pragma unroll
    for (int nb = 0; nb < 4; nb++) acc[nb] = (f32x4){0.f, 0.f, 0.f, 0.f};

    const int wrow = rs * 16 + lm;    // this wave's A row for lane

    for (int ch = 0; ch < 9; ch++) {
        __syncthreads();              // prev phase-2 reads done / stage A done
        // Phase 1: this wave produces V rows [ch*64 + rs*16, +16)
        union { short s[16]; bf16x8 v[2]; } u;
#pragma unroll
        for (int i = 0; i < 16; i++) {
            int kkg = ch * 64 + rs * 16 + i;           // wave-uniform
            int c = (kkg * 7282) >> 16;                // kkg/9 (exact for <5832)
            int k = kkg - c * 9;
            int4   id = sIdx[(k << 6) + l];
            float4 w  = sWt [(k << 6) + l];
            const float* xq = xb + ((size_t)c << 14);  // scalar base
            u.s[i] = f2bf(w.x * xq[id.x] + w.y * xq[id.y]
                        + w.z * xq[id.z] + w.w * xq[id.w]);
        }
        {
            bf16x8* dst = (bf16x8*)&V[l * VSTR + rs * 16];
            dst[0] = u.v[0];
            dst[1] = u.v[1];
        }
        __syncthreads();
        // Phase 2: 8 MFMAs
#pragma unroll
        for (int ks = 0; ks < 2; ks++) {
            bf16x8 a = *(const bf16x8*)(wb + wrow * 576 + ch * 64 + ks * 32 + quad * 8);
#pragma unroll
            for (int nb = 0; nb < 4; nb++) {
                bf16x8 bf = *(const bf16x8*)&V[(nb * 16 + lm) * VSTR + ks * 32 + quad * 8];
                acc[nb] = __builtin_amdgcn_mfma_f32_16x16x32_bf16(a, bf, acc[nb], 0, 0, 0);
            }
        }
    }

    const int wo = blockIdx.x * 16 + lm;
#pragma unroll
    for (int nb = 0; nb < 4; nb++) {
        int ho = blockIdx.y * 4 + nb;
        float* op = out + ((size_t)(b * Oo + rs * 16 + quad * 4) << 14) + (ho << 7) + wo;
#pragma unroll
        for (int reg = 0; reg < 4; reg++)
            op[(size_t)reg << 14] = acc[nb][reg];
    }
}

// ---------------------------------------------------------------------------
extern "C" void kernel_launch(void* const* d_in, const int* in_sizes, int n_in,
                              void* d_out, int out_size, void* d_ws, size_t ws_size,
                              hipStream_t stream) {
    const float* x     = (const float*)d_in[0];
    const float* guide = (const float*)d_in[1];
    const float* w_off = (const float*)d_in[2];
    const float* b_off = (const float*)d_in[3];
    const float* w_mod = (const float*)d_in[4];
    const float* b_mod = (const float*)d_in[5];
    const float* w_reg = (const float*)d_in[6];
    float* out = (float*)d_out;
    float* ws  = (float*)d_ws;

    hipLaunchKernelGGL(prep_weights, dim3((Oo * Cc * KK + 255) / 256), dim3(256),
                       0, stream, w_off, w_mod, w_reg, ws);

    const bool big = ws_size >= (size_t)WS_NEED_FLOATS * sizeof(float);
    const float* par_base;
    if (big) {
        hipLaunchKernelGGL(conv_partial, dim3(Ww / TS, Hh / TS, Bn * NSPL), dim3(256),
                           0, stream, x, guide, ws, ws + PART_OFF);
        hipLaunchKernelGGL(reduce_par, dim3(Bn * HW / 256), dim3(256),
                           0, stream, ws + PART_OFF, b_off, b_mod, ws + PAR2_OFF);
        par_base = ws + PAR2_OFF;
    } else {
        hipLaunchKernelGGL(conv_offmod, dim3(Ww / TS, Hh / TS, Bn), dim3(256),
                           0, stream, x, guide, b_off, b_mod, ws);
        par_base = ws + PAR1_OFF;
    }

    hipLaunchKernelGGL(deform_mfma, dim3(Ww / 16, Hh / 4, Bn), dim3(256),
                       0, stream, x, ws, par_base, out);
}

// Round 5
// 218.060 us; speedup vs baseline: 3.6969x; 1.5548x over previous
//
#include <hip/hip_runtime.h>
#include <math.h>

// Problem constants
#define Bn   4
#define Cc   64
#define Hh   128
#define Ww   128
#define Oo   64
#define HW   16384
#define CIN  128
#define KK   9
#define NPAR 27

// Workspace layout (float offsets)
#define WB2_OFF 0        // bf16 W2[32][1152] = 36864 shorts = 18432 float slots
#define WB_OFF  18432    // bf16 W [64][576]  = 36864 shorts = 18432 float slots
#define PAR_OFF 36864    // f32 par[B][27][HW]

typedef __attribute__((ext_vector_type(8))) short bf16x8;
typedef __attribute__((ext_vector_type(4))) float f32x4;
typedef __attribute__((ext_vector_type(2), aligned(4))) float f32x2u;  // 4B-aligned pair

__device__ __forceinline__ short f2bf(float f) {
    unsigned u = __builtin_bit_cast(unsigned, f);
    u += 0x7FFFu + ((u >> 16) & 1u);        // RNE
    return (short)(u >> 16);
}

// ---------------------------------------------------------------------------
// Prepass: bf16 weight copies. Flat layouts line up:
//   wb2[j][c*9+k]: rows 0-17 = w_off flat, 18-26 = w_mod flat, 27-31 = 0
//   wb [o][c*9+k]: = w_reg flat
// ---------------------------------------------------------------------------
__global__ void prep_weights(const float* __restrict__ w_off,
                             const float* __restrict__ w_mod,
                             const float* __restrict__ w_reg,
                             float* __restrict__ ws) {
    int i = blockIdx.x * 256 + threadIdx.x;
    short* wb2 = (short*)(ws + WB2_OFF);
    short* wb  = (short*)(ws + WB_OFF);
    if (i < 32 * 1152) {
        int j = i / 1152;
        float v = 0.f;
        if (j < 18)      v = w_off[i];
        else if (j < 27) v = w_mod[i - 18 * 1152];
        wb2[i] = f2bf(v);
    }
    if (i < 64 * 576) wb[i] = f2bf(w_reg[i]);
}

// ---------------------------------------------------------------------------
// conv_mfma: 3x3 conv 128->27(pad 32) via MFMA per 16x4-pixel tile.
// C[32][64] = W2[32][1152] x V[1152][64], K chunked 18x64 (kkg = c*9+k,
// wave-uniform per step -> scalar plane base). Phase 1: direct bounds-checked
// loads -> bf16 V_T[px][kk] in LDS. Phase 2: wave w owns n-tile (16 px),
// computes both 16-row m-tiles. Epilogue: per-element transform of D into
// sampling params (py/px/mask) -> par, fusing bias+coords+sigmoid (no
// reduce kernel). Layouts (m89/m120-verified): A[m=lane&15][k=quad*8+j],
// B[k=quad*8+j][n=lane&15], D[row=quad*4+reg][col=lane&15].
// ---------------------------------------------------------------------------
#define VSTR 72   // V_T row stride in bf16 (64 + 8 pad -> 2-way banks, free)

__global__ __launch_bounds__(256)
void conv_mfma(const float* __restrict__ x, const float* __restrict__ g,
               const float* __restrict__ ws_,
               const float* __restrict__ b_off, const float* __restrict__ b_mod,
               float* __restrict__ parw) {
    __shared__ __align__(16) short V[64 * VSTR];

    const int tid = threadIdx.x;
    const int l = tid & 63, lm = l & 15, quad = l >> 4;
    const int w = __builtin_amdgcn_readfirstlane(tid >> 6);   // wave = n-tile
    const int b = blockIdx.z;
    const int ho0 = blockIdx.y * 4, wo0 = blockIdx.x * 16;
    const int ho_l = ho0 + (l >> 4), wo_l = wo0 + lm;         // staging pixel l

    const short* wb2 = (const short*)(ws_ + WB2_OFF);

    f32x4 acc0 = {0.f, 0.f, 0.f, 0.f}, acc1 = {0.f, 0.f, 0.f, 0.f};

    for (int cc = 0; cc < 18; cc++) {
        __syncthreads();
        union { short s[16]; bf16x8 v[2]; } u;
#pragma unroll
        for (int i = 0; i < 16; i++) {
            int kkg = cc * 64 + w * 16 + i;       // wave-uniform
            int c = (kkg * 7282) >> 16;           // kkg/9 exact for <5832
            int k = kkg - c * 9;
            int dy = k / 3, dx = k - dy * 3;
            const float* plane = (c < Cc) ? (x + ((size_t)(b * Cc + c) << 14))
                                          : (g + ((size_t)(b * Cc + c - Cc) << 14));
            int y = ho_l + dy - 1, xx = wo_l + dx - 1;
            bool ok = ((unsigned)y < 128u) && ((unsigned)xx < 128u);
            int cy = min(max(y, 0), 127), cx = min(max(xx, 0), 127);
            float val = plane[(cy << 7) + cx];
            u.s[i] = f2bf(ok ? val : 0.f);
        }
        {
            bf16x8* dst = (bf16x8*)&V[l * VSTR + w * 16];
            dst[0] = u.v[0];
            dst[1] = u.v[1];
        }
        __syncthreads();
#pragma unroll
        for (int ks = 0; ks < 2; ks++) {
            bf16x8 bfr = *(const bf16x8*)&V[(w * 16 + lm) * VSTR + ks * 32 + quad * 8];
            bf16x8 a0 = *(const bf16x8*)(wb2 + lm * 1152 + cc * 64 + ks * 32 + quad * 8);
            bf16x8 a1 = *(const bf16x8*)(wb2 + (16 + lm) * 1152 + cc * 64 + ks * 32 + quad * 8);
            acc0 = __builtin_amdgcn_mfma_f32_16x16x32_bf16(a0, bfr, acc0, 0, 0, 0);
            acc1 = __builtin_amdgcn_mfma_f32_16x16x32_bf16(a1, bfr, acc1, 0, 0, 0);
        }
    }

    // Epilogue: D[row j][col lm] -> par channels, fused bias/coords/sigmoid
    const int ho = ho0 + w, wo = wo0 + lm;
    const int pix = (ho << 7) + wo;
    float* par = parw + (size_t)b * NPAR * HW + pix;
#pragma unroll
    for (int mt = 0; mt < 2; mt++) {
        f32x4 a = mt ? acc1 : acc0;
#pragma unroll
        for (int reg = 0; reg < 4; reg++) {
            int j = mt * 16 + quad * 4 + reg;
            float v = a[reg];
            if (j < 18) {
                int k = j >> 1;
                float vb = v + b_off[j];
                if (j & 1) par[(size_t)(9 + k) * HW] = vb + (float)(k - (k / 3) * 3 + wo - 1);
                else       par[(size_t)k * HW]       = vb + (float)(k / 3 + ho - 1);
            } else if (j < 27) {
                int k = j - 18;
                par[(size_t)(18 + k) * HW] = 2.f / (1.f + __expf(-(v + b_mod[k])));
            }
        }
    }
}

// ---------------------------------------------------------------------------
// deform_mfma: C[64o][64px] = W[64][576] x V[576][64] per 16x4-px tile.
// Stage A: bilinear params; x-corner pairs folded into pre-transformed
// weights (wa -> p.x, wb -> p.y) so phase 1 is 2 dwordx2 loads + 4 FMA per
// element (no selects). K chunked 9x64. Phase 2: wave rs owns out rows
// [16rs,+16), B via ds_read_b128, fp32 accum.
// ---------------------------------------------------------------------------
__global__ __launch_bounds__(256, 6)
void deform_mfma(const float* __restrict__ x, const float* __restrict__ ws_,
                 const float* __restrict__ par_base, float* __restrict__ out) {
    __shared__ int2   sIdx[576];
    __shared__ float4 sWt [576];
    __shared__ __align__(16) short V[64 * VSTR];

    const int tid = threadIdx.x;
    const int l = tid & 63;
    const int lm = l & 15, quad = l >> 4;
    const int rs = __builtin_amdgcn_readfirstlane(tid >> 6);   // wave id
    const int b = blockIdx.z;

    const float* par = par_base + (size_t)b * NPAR * HW;
    const short* wb  = (const short*)(ws_ + WB_OFF);
    const float* xb  = x + ((size_t)(b * Cc) << 14);

    // Stage A: bilinear params for 9 taps x 64 pixels
    for (int s = tid; s < 576; s += 256) {
        int k = s >> 6;
        int sl = s & 63;
        int sho = blockIdx.y * 4 + (sl >> 4);
        int swo = blockIdx.x * 16 + (sl & 15);
        int spix = (sho << 7) + swo;
        float py = par[(size_t)k * HW + spix];
        float px = par[(size_t)(9 + k) * HW + spix];
        float m  = par[(size_t)(18 + k) * HW + spix];
        float fy = floorf(py), fx = floorf(px);
        int y0 = (int)fy, x0 = (int)fx;
        int y1 = y0 + 1;
        float wy1 = py - fy, wx1 = px - fx;
        float wy0 = 1.f - wy1, wx0 = 1.f - wx1;
        bool vy0 = (unsigned)y0 < 128u, vy1 = (unsigned)y1 < 128u;
        bool vx0 = (unsigned)x0 < 128u, vx1 = (unsigned)(x0 + 1) < 128u;
        int cy0 = min(max(y0, 0), 127), cy1 = min(max(y1, 0), 127);
        int bx2 = min(max(x0, 0), 126);
        bool sel_lo = (x0 < 0), sel_hi = (x0 > 126);
        float w00 = (vy0 && vx0) ? wy0 * wx0 * m : 0.f;
        float w01 = (vy0 && vx1) ? wy0 * wx1 * m : 0.f;
        float w10 = (vy1 && vx0) ? wy1 * wx0 * m : 0.f;
        float w11 = (vy1 && vx1) ? wy1 * wx1 * m : 0.f;
        // fold boundary handling into pair weights: wa->[bx2], wb->[bx2+1]
        float wa0 = sel_lo ? w01 : (sel_hi ? 0.f : w00);
        float wb0 = sel_hi ? w00 : (sel_lo ? 0.f : w01);
        float wa1 = sel_lo ? w11 : (sel_hi ? 0.f : w10);
        float wb1 = sel_hi ? w10 : (sel_lo ? 0.f : w11);
        sIdx[s] = make_int2((cy0 << 7) + bx2, (cy1 << 7) + bx2);
        sWt[s]  = make_float4(wa0, wb0, wa1, wb1);
    }

    f32x4 acc[4];
#pragma unroll
    for (int nb = 0; nb < 4; nb++) acc[nb] = (f32x4){0.f, 0.f, 0.f, 0.f};

    const int wrow = rs * 16 + lm;    // this wave's A row for lane

    for (int ch = 0; ch < 9; ch++) {
        __syncthreads();              // prev phase-2 reads done / stage A done
        union { short s[16]; bf16x8 v[2]; } u;
#pragma unroll
        for (int i = 0; i < 16; i++) {
            int kkg = ch * 64 + rs * 16 + i;           // wave-uniform
            int c = (kkg * 7282) >> 16;                // kkg/9
            int k = kkg - c * 9;
            int2   id = sIdx[(k << 6) + l];
            float4 wv = sWt [(k << 6) + l];
            const float* xq = xb + ((size_t)c << 14);  // scalar base
            f32x2u p0 = *(const f32x2u*)(xq + id.x);
            f32x2u p1 = *(const f32x2u*)(xq + id.y);
            u.s[i] = f2bf(wv.x * p0.x + wv.y * p0.y + wv.z * p1.x + wv.w * p1.y);
        }
        {
            bf16x8* dst = (bf16x8*)&V[l * VSTR + rs * 16];
            dst[0] = u.v[0];
            dst[1] = u.v[1];
        }
        __syncthreads();
#pragma unroll
        for (int ks = 0; ks < 2; ks++) {
            bf16x8 a = *(const bf16x8*)(wb + wrow * 576 + ch * 64 + ks * 32 + quad * 8);
#pragma unroll
            for (int nb = 0; nb < 4; nb++) {
                bf16x8 bf = *(const bf16x8*)&V[(nb * 16 + lm) * VSTR + ks * 32 + quad * 8];
                acc[nb] = __builtin_amdgcn_mfma_f32_16x16x32_bf16(a, bf, acc[nb], 0, 0, 0);
            }
        }
    }

    const int wo = blockIdx.x * 16 + lm;
#pragma unroll
    for (int nb = 0; nb < 4; nb++) {
        int ho = blockIdx.y * 4 + nb;
        float* op = out + ((size_t)(b * Oo + rs * 16 + quad * 4) << 14) + (ho << 7) + wo;
#pragma unroll
        for (int reg = 0; reg < 4; reg++)
            op[(size_t)reg << 14] = acc[nb][reg];
    }
}

// ---------------------------------------------------------------------------
extern "C" void kernel_launch(void* const* d_in, const int* in_sizes, int n_in,
                              void* d_out, int out_size, void* d_ws, size_t ws_size,
                              hipStream_t stream) {
    const float* x     = (const float*)d_in[0];
    const float* guide = (const float*)d_in[1];
    const float* w_off = (const float*)d_in[2];
    const float* b_off = (const float*)d_in[3];
    const float* w_mod = (const float*)d_in[4];
    const float* b_mod = (const float*)d_in[5];
    const float* w_reg = (const float*)d_in[6];
    float* out = (float*)d_out;
    float* ws  = (float*)d_ws;

    hipLaunchKernelGGL(prep_weights, dim3((32 * 1152 + 255) / 256), dim3(256),
                       0, stream, w_off, w_mod, w_reg, ws);
    hipLaunchKernelGGL(conv_mfma, dim3(Ww / 16, Hh / 4, Bn), dim3(256),
                       0, stream, x, guide, ws, b_off, b_mod, ws + PAR_OFF);
    hipLaunchKernelGGL(deform_mfma, dim3(Ww / 16, Hh / 4, Bn), dim3(256),
                       0, stream, x, ws, ws + PAR_OFF, out);
}